// Round 7
// baseline (235.060 us; speedup 1.0000x reference)
//
#include <hip/hip_runtime.h>
#include <math.h>

// Problem constants (fixed by setup_inputs)
#define BATCH 8
#define CH    256
#define H     128
#define W     128
#define PLANE (H * W)            // 16384
#define NPIX  (BATCH * PLANE)    // 131072
#define NSHIFT 12                // symmetric half of the 24 shifts
#define NMAPS  13                // 12 shifted dots + normsq
#define NCHUNK 8                 // channel chunks
#define CPC    (CH / NCHUNK)     // 32 channels per chunk
#define TROWS  8                 // output rows per block
#define NTILE  (H / TROWS)       // 16
#define NZ4    (NMAPS * NPIX / 4)  // float4s to zero in comb

// 12 "positive" shifts: dy>0 or (dy==0 && dx>0). Negatives recovered by symmetry.
// map order: 0:(0,1) 1:(0,2) 2..6:(1,-2..2) 7..11:(2,-2..2)  [12 = normsq]
static __device__ __constant__ int S_DY[NSHIFT] = {0,0,1,1,1,1,1,2,2,2,2,2};
static __device__ __constant__ int S_DX[NSHIFT] = {1,2,-2,-1,0,1,2,-2,-1,0,1,2};

#define NCORRB (BATCH * NTILE * NCHUNK)          // 1024 corr blocks
#define NSTATB (BATCH * 64)                      // 512 stats blocks

__device__ __forceinline__ void fma4(float& acc, const float4& a, const float4& b) {
    acc = fmaf(a.x, b.x, acc);
    acc = fmaf(a.y, b.y, acc);
    acc = fmaf(a.z, b.z, acc);
    acc = fmaf(a.w, b.w, acc);
}

// ---------------------------------------------------------------------------
// Kernel P: zero comb (atomic accumulator target) + cnt/inc/out
// ---------------------------------------------------------------------------
__global__ __launch_bounds__(256) void k_prep(float4* __restrict__ comb4,
                                              int* __restrict__ cnt,
                                              int* __restrict__ inc,
                                              float* __restrict__ out) {
    int i = blockIdx.x * 256 + threadIdx.x;
    if (i < NZ4) comb4[i] = make_float4(0.f, 0.f, 0.f, 0.f);
    if (blockIdx.x == 0) {
        int t = threadIdx.x;
        if (t < 8) { cnt[t] = 0; inc[t] = 0; }
        if (t == 0) out[0] = 0.0f;
    }
}

// ---------------------------------------------------------------------------
// Kernel C: fused correlation + per-image stats.
// Corr blocks [0,NCORRB): decode chunk(8) | tile(16) | b(8).
//   Block covers 8 output rows x 128 px; stages 10 rows x 4 channels as
//   float4(=4ch)-per-pixel in LDS (the measured conflict-free pattern).
//   Each thread: 4 adjacent output rows x 1 px -> 52 accumulators; per stage
//   28 b128 reads + 5 writes feed 208 FMAs. Register-prefetch pipeline for
//   the next 4-channel stage. 16 barriers/block (half of R6).
// Stats blocks [NCORRB, NCORRB+NSTATB): per-image cnt/inc.
// __launch_bounds__(256,3): VGPR cap 170 — guarantees no spill; if actual
// usage <=128 HW still schedules 4 blocks/CU.
// ---------------------------------------------------------------------------
__global__ __launch_bounds__(256, 3) void k_corr(const float* __restrict__ er,
                                                 const int* __restrict__ seg,
                                                 const int* __restrict__ gtb,
                                                 float* __restrict__ comb,
                                                 int* __restrict__ cnt,
                                                 int* __restrict__ inc) {
    __shared__ float4 lds[10][132];   // 10 staged rows, x padded by 2 each side
    int t = threadIdx.x;

    if (blockIdx.x >= NCORRB) {
        // ---- stats path ----
        int blk2 = blockIdx.x - NCORRB;
        int b = blk2 >> 6;
        int i = (blk2 & 63) * 256 + t;
        int my_cnt = 0, my_any = 0;
        {
            int s = seg[b * PLANE + i];
            int g = gtb[b * PLANE + i];
            int s0 = (s == 255) ? 0 : s;
            int g0 = (g == 255) ? 0 : g;
            if (s0 > 0 && g0 > 0) {
                my_any = 1;
                int y = i >> 7, x = i & 127;
                if (y >= 2 && y < H - 2 && x >= 2 && x < W - 2) my_cnt = 1;
            }
        }
        for (int o = 32; o > 0; o >>= 1) {
            my_cnt += __shfl_down(my_cnt, o, 64);
            my_any |= __shfl_down(my_any, o, 64);
        }
        __shared__ int sc[4], sa[4];
        int lane = t & 63, wid = t >> 6;
        if (lane == 0) { sc[wid] = my_cnt; sa[wid] = my_any; }
        __syncthreads();
        if (t == 0) {
            int c = sc[0] + sc[1] + sc[2] + sc[3];
            int a = sa[0] | sa[1] | sa[2] | sa[3];
            if (c) atomicAdd(&cnt[b], c);
            if (a) atomicOr(&inc[b], 1);
        }
        return;
    }

    // ---- correlation path ----
    int blk = blockIdx.x;
    int chunk = blk & 7;
    int tile  = (blk >> 3) & 15;
    int b     = blk >> 7;
    int y0 = tile * TROWS;           // block covers output rows y0..y0+7
    int c0 = chunk * CPC;
    int r = t >> 7;                  // thread owns output rows y0+4r .. y0+4r+3
    int x = t & 127;

    // zero the 40 x-pad slots once (first in-loop barrier makes them visible)
    if (t < 40) {
        int row = t >> 2, col = t & 3;
        int xs = (col < 2) ? col : (col + 128);   // 0,1,130,131
        lds[row][xs] = make_float4(0.f, 0.f, 0.f, 0.f);
    }

    float acc[4][13];
#pragma unroll
    for (int o = 0; o < 4; ++o)
#pragma unroll
        for (int m = 0; m < 13; ++m) acc[o][m] = 0.0f;

    const float* base = er + (size_t)b * CH * PLANE;

    // prefetch registers: 5 stage slots x 4 channels
    float pf[5][4];
    auto load_quad = [&](int c) {
#pragma unroll
        for (int k = 0; k < 5; ++k) {
            int s = t + k * 256;         // 0..1279
            int row = s >> 7;            // 0..9
            int xs = s & 127;
            int y = y0 + row;
            if (y < H) {
                const float* p0 = base + (size_t)c * PLANE + y * W + xs;
                pf[k][0] = p0[0];
                pf[k][1] = p0[PLANE];
                pf[k][2] = p0[2 * PLANE];
                pf[k][3] = p0[3 * PLANE];
            } else {
                pf[k][0] = 0.f; pf[k][1] = 0.f; pf[k][2] = 0.f; pf[k][3] = 0.f;
            }
        }
    };

    load_quad(c0);
    const int iters = CPC / 4;       // 8
    for (int it = 0; it < iters; ++it) {
        __syncthreads();   // prior iter's LDS reads done
        // commit prefetched quad to LDS (vmcnt wait lands here, after overlap)
        float4* lf = (float4*)lds;
#pragma unroll
        for (int k = 0; k < 5; ++k) {
            int s = t + k * 256;
            int row = s >> 7;
            int xs = s & 127;
            lf[row * 132 + xs + 2] = make_float4(pf[k][0], pf[k][1], pf[k][2], pf[k][3]);
        }
        __syncthreads();
        if (it + 1 < iters) load_quad(c0 + 4 * (it + 1));   // overlaps compute below

        // liveness-structured sweep over staged rows j = 0..5 (rel to 4r):
        // row j feeds output o=j (self), o=j-1 (dy=1), o=j-2 (dy=2)
        const float4* colp = &lds[4 * r][x + 2];
        float4 cen[4];
#pragma unroll
        for (int j = 0; j < 6; ++j) {
            const float4* row = colp + j * 132;
            float4 c0v = row[0], p1 = row[1], p2 = row[2];
            float4 m1 = make_float4(0.f,0.f,0.f,0.f), m2 = m1;
            if (j >= 1) { m1 = row[-1]; m2 = row[-2]; }
            if (j < 4) {
                cen[j] = c0v;
                fma4(acc[j][12], c0v, c0v);
                fma4(acc[j][0],  c0v, p1);
                fma4(acc[j][1],  c0v, p2);
            }
            if (j >= 1 && j <= 4) {
                float4 a = cen[j - 1];
                fma4(acc[j-1][2], a, m2);
                fma4(acc[j-1][3], a, m1);
                fma4(acc[j-1][4], a, c0v);
                fma4(acc[j-1][5], a, p1);
                fma4(acc[j-1][6], a, p2);
            }
            if (j >= 2) {
                float4 a = cen[j - 2];
                fma4(acc[j-2][7],  a, m2);
                fma4(acc[j-2][8],  a, m1);
                fma4(acc[j-2][9],  a, c0v);
                fma4(acc[j-2][10], a, p1);
                fma4(acc[j-2][11], a, p2);
            }
        }
    }

    // atomic accumulation into the combined maps (NCHUNK contenders/address)
#pragma unroll
    for (int o = 0; o < 4; ++o) {
        int pix = b * PLANE + (y0 + 4 * r + o) * W + x;
#pragma unroll
        for (int m = 0; m < NSHIFT; ++m)
            atomicAdd(&comb[m * NPIX + pix], acc[o][m]);
        atomicAdd(&comb[NSHIFT * NPIX + pix], acc[o][12]);
    }
}

// ---------------------------------------------------------------------------
// Kernel L: per-valid-pixel loss assembly (factor computed inline) + reduce
// comb layout: maps 0..11 = shifted dots (S order), map 12 = normsq
// ---------------------------------------------------------------------------
__global__ __launch_bounds__(256) void k_loss(const float* __restrict__ comb,
                                              const int* __restrict__ seg,
                                              const int* __restrict__ gtb,
                                              const int* __restrict__ cnt,
                                              const int* __restrict__ inc,
                                              float* __restrict__ out) {
    const float* dots   = comb;
    const float* normsq = comb + NSHIFT * NPIX;
    int idx = blockIdx.x * 256 + threadIdx.x;
    int b = idx >> 14;
    int rem = idx & (PLANE - 1);
    int y = rem >> 7;
    int x = rem & 127;

    // factor = inc_b ? 1/(24 * max(cnt_b,1) * scale_num) : 0  (uniform per block)
    int sn = 0;
#pragma unroll
    for (int b2 = 0; b2 < BATCH; b2++) sn += (inc[b2] != 0);
    if (sn < 1) sn = 1;
    int cb = cnt[b]; if (cb < 1) cb = 1;
    float factor = inc[b] ? 1.0f / (24.0f * (float)cb * (float)sn) : 0.0f;

    float val = 0.0f;
    if (y >= 2 && y < H - 2 && x >= 2 && x < W - 2) {
        int sp = seg[idx];
        int gp = gtb[idx];
        int s0 = (sp == 255) ? 0 : sp;
        int g0 = (gp == 255) ? 0 : gp;
        if (s0 > 0 && g0 > 0) {
            float np = fmaxf(sqrtf(normsq[idx]), 1e-8f);
            float sum = 0.0f;
#pragma unroll
            for (int i = 0; i < NSHIFT; ++i) {
                int off = S_DY[i] * W + S_DX[i];
                // + shift: cos(p, p+d)
                {
                    float d  = dots[i * NPIX + idx];
                    float nn = fmaxf(sqrtf(normsq[idx + off]), 1e-8f);
                    float cosv = d / (np * nn);
                    int sq = seg[idx + off];
                    float lab = (sp == sq && sp < 2) ? 1.0f : 0.0f;
                    float tt = cosv - lab;
                    sum = fmaf(tt, tt, sum);
                }
                // - shift: cos(p, p-d) = dot_d(p-d)/(norm(p)norm(p-d))
                {
                    float d  = dots[i * NPIX + idx - off];
                    float nn = fmaxf(sqrtf(normsq[idx - off]), 1e-8f);
                    float cosv = d / (np * nn);
                    int sq = seg[idx - off];
                    float lab = (sp == sq && sp < 2) ? 1.0f : 0.0f;
                    float tt = cosv - lab;
                    sum = fmaf(tt, tt, sum);
                }
            }
            val = sum * factor;
        }
    }

    // block reduction: wave shuffle then LDS across 4 waves
    for (int o = 32; o > 0; o >>= 1)
        val += __shfl_down(val, o, 64);
    __shared__ float wsum[4];
    int lane = threadIdx.x & 63;
    int wid  = threadIdx.x >> 6;
    if (lane == 0) wsum[wid] = val;
    __syncthreads();
    if (threadIdx.x == 0) {
        float s = wsum[0] + wsum[1] + wsum[2] + wsum[3];
        atomicAdd(out, s);
    }
}

// ---------------------------------------------------------------------------
extern "C" void kernel_launch(void* const* d_in, const int* in_sizes, int n_in,
                              void* d_out, int out_size, void* d_ws, size_t ws_size,
                              hipStream_t stream) {
    const float* er  = (const float*)d_in[0];
    const int*   seg = (const int*)d_in[1];
    const int*   gtb = (const int*)d_in[2];
    float* out = (float*)d_out;

    float* ws   = (float*)d_ws;
    float* comb = ws;                            // 13 * NPIX floats (6.8 MB)
    int*   cnt  = (int*)(comb + NMAPS * NPIX);   // 8 ints
    int*   inc  = cnt + 8;                       // 8 ints

    hipLaunchKernelGGL(k_prep, dim3((NZ4 + 255) / 256), dim3(256), 0, stream,
                       (float4*)comb, cnt, inc, out);
    hipLaunchKernelGGL(k_corr, dim3(NCORRB + NSTATB), dim3(256), 0, stream,
                       er, seg, gtb, comb, cnt, inc);
    hipLaunchKernelGGL(k_loss, dim3(NPIX / 256), dim3(256), 0, stream,
                       comb, seg, gtb, cnt, inc, out);
}

// Round 8
// 232.953 us; speedup vs baseline: 1.0090x; 1.0090x over previous
//
#include <hip/hip_runtime.h>
#include <math.h>

// Problem constants (fixed by setup_inputs)
#define BATCH 8
#define CH    256
#define H     128
#define W     128
#define PLANE (H * W)            // 16384
#define NPIX  (BATCH * PLANE)    // 131072
#define NSHIFT 12                // symmetric half of the 24 shifts
#define NMAPS  13                // 12 shifted dots + normsq
#define NCHUNK 8                 // channel chunks (2048 corr blocks -> ~8/CU)
#define CPC    (CH / NCHUNK)     // 32 channels per chunk
#define NZ4    (NMAPS * NPIX / 4)  // float4s to zero in comb

// map order: 0:(0,1) 1:(0,2) 2..6:(1,-2..2) 7..11:(2,-2..2)  [12 = normsq]

#define NCORRB (BATCH * 32 * NCHUNK)             // 2048 corr blocks
#define NSTATB (BATCH * 64)                      // 512 stats blocks

__device__ __forceinline__ void fma4(float& acc, const float4& a, const float4& b) {
    acc = fmaf(a.x, b.x, acc);
    acc = fmaf(a.y, b.y, acc);
    acc = fmaf(a.z, b.z, acc);
    acc = fmaf(a.w, b.w, acc);
}

// ---------------------------------------------------------------------------
// Kernel P: zero comb (atomic accumulator target) + cnt/inc/out
// ---------------------------------------------------------------------------
__global__ __launch_bounds__(256) void k_prep(float4* __restrict__ comb4,
                                              int* __restrict__ cnt,
                                              int* __restrict__ inc,
                                              float* __restrict__ out) {
    int i = blockIdx.x * 256 + threadIdx.x;
    if (i < NZ4) comb4[i] = make_float4(0.f, 0.f, 0.f, 0.f);
    if (blockIdx.x == 0) {
        int t = threadIdx.x;
        if (t < 8) { cnt[t] = 0; inc[t] = 0; }
        if (t == 0) out[0] = 0.0f;
    }
}

// ---------------------------------------------------------------------------
// Kernel C: fused correlation + per-image stats. (R6 inner structure, NCHUNK=8)
// Corr blocks [0,NCORRB): decode chunk(8) | tile(32) | b(8).
//   256 thr; each thread computes 2 adjacent output rows (block covers 4
//   rows, stages 6 rows x 4 channels as float4(=4ch)-per-pixel in LDS — the
//   measured conflict-free pattern). Register prefetch of the next quad
//   overlaps compute. atomicAdd into combined maps (8 contenders/address).
// Stats blocks [NCORRB, NCORRB+NSTATB): per-image cnt/inc.
// ---------------------------------------------------------------------------
__global__ __launch_bounds__(256, 4) void k_corr(const float* __restrict__ er,
                                                 const int* __restrict__ seg,
                                                 const int* __restrict__ gtb,
                                                 float* __restrict__ comb,
                                                 int* __restrict__ cnt,
                                                 int* __restrict__ inc) {
    __shared__ float4 lds[6][132];   // 6 staged rows, x padded by 2 each side
    int t = threadIdx.x;

    if (blockIdx.x >= NCORRB) {
        // ---- stats path ----
        int blk2 = blockIdx.x - NCORRB;
        int b = blk2 >> 6;
        int i = (blk2 & 63) * 256 + t;
        int my_cnt = 0, my_any = 0;
        {
            int s = seg[b * PLANE + i];
            int g = gtb[b * PLANE + i];
            int s0 = (s == 255) ? 0 : s;
            int g0 = (g == 255) ? 0 : g;
            if (s0 > 0 && g0 > 0) {
                my_any = 1;
                int y = i >> 7, x = i & 127;
                if (y >= 2 && y < H - 2 && x >= 2 && x < W - 2) my_cnt = 1;
            }
        }
        for (int o = 32; o > 0; o >>= 1) {
            my_cnt += __shfl_down(my_cnt, o, 64);
            my_any |= __shfl_down(my_any, o, 64);
        }
        __shared__ int sc[4], sa[4];
        int lane = t & 63, wid = t >> 6;
        if (lane == 0) { sc[wid] = my_cnt; sa[wid] = my_any; }
        __syncthreads();
        if (t == 0) {
            int c = sc[0] + sc[1] + sc[2] + sc[3];
            int a = sa[0] | sa[1] | sa[2] | sa[3];
            if (c) atomicAdd(&cnt[b], c);
            if (a) atomicOr(&inc[b], 1);
        }
        return;
    }

    // ---- correlation path ----
    int blk = blockIdx.x;
    int chunk = blk & 7;
    int tile  = (blk >> 3) & 31;
    int b     = blk >> 8;
    int y0 = tile * 4;               // block covers output rows y0..y0+3
    int c0 = chunk * CPC;
    int r = t >> 7;                  // thread handles output rows y0+2r, y0+2r+1
    int x = t & 127;

    // zero the x-pad slots once (first in-loop barrier makes them visible)
    if (t < 24) {
        int row = t >> 2, col = t & 3;
        int xs = (col < 2) ? col : (col + 128);   // 0,1,130,131
        lds[row][xs] = make_float4(0.f, 0.f, 0.f, 0.f);
    }

    float accA[13], accB[13];
#pragma unroll
    for (int i = 0; i < 13; i++) { accA[i] = 0.0f; accB[i] = 0.0f; }

    const float* base = er + (size_t)b * CH * PLANE;

    // prefetch registers: 3 stage slots x 4 channels
    float pf[3][4];
    auto load_quad = [&](int c) {
#pragma unroll
        for (int k = 0; k < 3; ++k) {
            int s = t + k * 256;         // 0..767
            int row = s >> 7;            // 0..5
            int xs = s & 127;
            int y = y0 + row;
            if (y < H) {
                const float* p0 = base + (size_t)c * PLANE + y * W + xs;
                pf[k][0] = p0[0];
                pf[k][1] = p0[PLANE];
                pf[k][2] = p0[2 * PLANE];
                pf[k][3] = p0[3 * PLANE];
            } else {
                pf[k][0] = 0.f; pf[k][1] = 0.f; pf[k][2] = 0.f; pf[k][3] = 0.f;
            }
        }
    };

    load_quad(c0);
    const int iters = CPC / 4;       // 8
    for (int it = 0; it < iters; ++it) {
        __syncthreads();   // prior iter's LDS reads done
        // commit prefetched quad to LDS (vmcnt wait lands here, after overlap)
#pragma unroll
        for (int k = 0; k < 3; ++k) {
            int s = t + k * 256;
            int row = s >> 7;
            int xs = s & 127;
            lds[row][xs + 2] = make_float4(pf[k][0], pf[k][1], pf[k][2], pf[k][3]);
        }
        __syncthreads();
        if (it + 1 < iters) load_quad(c0 + 4 * (it + 1));   // overlaps compute below

        const float4* lp = &lds[2 * r][x + 2];
        float4 cA = lp[0];               // (rel row 0, dx 0)
        float4 cB = lp[132];             // (rel row 1, dx 0)
        {
            float4 v1 = lp[1], v2 = lp[2];
            fma4(accA[12], cA, cA);
            fma4(accA[0],  cA, v1);
            fma4(accA[1],  cA, v2);
        }
        {
            float4 m2 = lp[130], m1 = lp[131], p1 = lp[133], p2 = lp[134];
            fma4(accA[2], cA, m2);
            fma4(accA[3], cA, m1);
            fma4(accA[4], cA, cB);
            fma4(accA[5], cA, p1);
            fma4(accA[6], cA, p2);
            fma4(accB[12], cB, cB);
            fma4(accB[0],  cB, p1);
            fma4(accB[1],  cB, p2);
        }
        {
            float4 m2 = lp[262], m1 = lp[263], v0 = lp[264], p1 = lp[265], p2 = lp[266];
            fma4(accA[7],  cA, m2);
            fma4(accA[8],  cA, m1);
            fma4(accA[9],  cA, v0);
            fma4(accA[10], cA, p1);
            fma4(accA[11], cA, p2);
            fma4(accB[2], cB, m2);
            fma4(accB[3], cB, m1);
            fma4(accB[4], cB, v0);
            fma4(accB[5], cB, p1);
            fma4(accB[6], cB, p2);
        }
        {
            float4 m2 = lp[394], m1 = lp[395], v0 = lp[396], p1 = lp[397], p2 = lp[398];
            fma4(accB[7],  cB, m2);
            fma4(accB[8],  cB, m1);
            fma4(accB[9],  cB, v0);
            fma4(accB[10], cB, p1);
            fma4(accB[11], cB, p2);
        }
    }

    // atomic accumulation into the combined maps (NCHUNK contenders/address)
    int pixA = b * PLANE + (y0 + 2 * r) * W + x;
    int pixB = pixA + W;
#pragma unroll
    for (int m = 0; m < NMAPS; ++m) {
        atomicAdd(&comb[m * NPIX + pixA], accA[m]);
        atomicAdd(&comb[m * NPIX + pixB], accB[m]);
    }
}

// ---------------------------------------------------------------------------
// k_loss helpers: load a 12-float / 12-int window (3 aligned quads) centered
// on this thread's 4-px quad; edge quads clamp to the center quad (their
// values are only ever consumed by invalid edge pixels).
// ---------------------------------------------------------------------------
__device__ __forceinline__ void ldrow_f(const float* p, int x0, float a[12]) {
    float4 u = *((const float4*)(x0 == 0   ? p : p - 4));
    float4 v = *((const float4*)p);
    float4 w = *((const float4*)(x0 == 124 ? p : p + 4));
    a[0]=u.x; a[1]=u.y; a[2]=u.z; a[3]=u.w;
    a[4]=v.x; a[5]=v.y; a[6]=v.z; a[7]=v.w;
    a[8]=w.x; a[9]=w.y; a[10]=w.z; a[11]=w.w;
}
__device__ __forceinline__ void ldrow_i(const int* p, int x0, int a[12]) {
    int4 u = *((const int4*)(x0 == 0   ? p : p - 4));
    int4 v = *((const int4*)p);
    int4 w = *((const int4*)(x0 == 124 ? p : p + 4));
    a[0]=u.x; a[1]=u.y; a[2]=u.z; a[3]=u.w;
    a[4]=v.x; a[5]=v.y; a[6]=v.z; a[7]=v.w;
    a[8]=w.x; a[9]=w.y; a[10]=w.z; a[11]=w.w;
}

// ---------------------------------------------------------------------------
// Kernel L: loss assembly, 4 px/thread, aligned float4 window loads.
// comb layout: maps 0..11 = shifted dots, map 12 = normsq
// ---------------------------------------------------------------------------
__global__ __launch_bounds__(256) void k_loss(const float* __restrict__ comb,
                                              const int* __restrict__ seg,
                                              const int* __restrict__ gtb,
                                              const int* __restrict__ cnt,
                                              const int* __restrict__ inc,
                                              float* __restrict__ out) {
    const float* dots   = comb;
    const float* normsq = comb + NSHIFT * NPIX;
    int idx0 = (blockIdx.x * 256 + threadIdx.x) * 4;   // 4-aligned pixel
    int b = idx0 >> 14;
    int rem = idx0 & (PLANE - 1);
    int y = rem >> 7;
    int x0 = rem & 127;

    // factor = inc_b ? 1/(24 * max(cnt_b,1) * scale_num) : 0
    int sn = 0;
#pragma unroll
    for (int b2 = 0; b2 < BATCH; b2++) sn += (inc[b2] != 0);
    if (sn < 1) sn = 1;
    int cb = cnt[b]; if (cb < 1) cb = 1;
    float factor = inc[b] ? 1.0f / (24.0f * (float)cb * (float)sn) : 0.0f;

    float val = 0.0f;
    if (y >= 2 && y <= H - 3) {
        int4 sc4 = *((const int4*)(seg + idx0));
        int4 gc4 = *((const int4*)(gtb + idx0));
        int sp[4] = {sc4.x, sc4.y, sc4.z, sc4.w};
        int gp[4] = {gc4.x, gc4.y, gc4.z, gc4.w};
        float4 nc4 = *((const float4*)(normsq + idx0));
        float ncv[4] = {nc4.x, nc4.y, nc4.z, nc4.w};
        float np[4], sum[4];
        bool vld[4];
#pragma unroll
        for (int j = 0; j < 4; ++j) {
            int s0 = (sp[j] == 255) ? 0 : sp[j];
            int g0 = (gp[j] == 255) ? 0 : gp[j];
            int xj = x0 + j;
            vld[j] = (s0 > 0 && g0 > 0 && xj >= 2 && xj <= W - 3);
            np[j] = fmaxf(sqrtf(ncv[j]), 1e-8f);
            sum[j] = 0.0f;
        }

        // ---- dy = 0 group (maps 0,1; dx = 1,2) ----
        {
            int sr0[12];
            float nr0[12], nn0[12];
            ldrow_i(seg + idx0, x0, sr0);
            ldrow_f(normsq + idx0, x0, nr0);
#pragma unroll
            for (int k = 0; k < 12; ++k) nn0[k] = fmaxf(sqrtf(nr0[k]), 1e-8f);
#pragma unroll
            for (int dx = 1; dx <= 2; ++dx) {
                int i = dx - 1;
                float dr[12];
                ldrow_f(dots + (size_t)i * NPIX + idx0, x0, dr);
#pragma unroll
                for (int j = 0; j < 4; ++j) {
                    // + shift: cos(p, p+d)
                    float lab = (sp[j] == sr0[j + dx + 4] && sp[j] < 2) ? 1.f : 0.f;
                    float cosv = dr[j + 4] / (np[j] * nn0[j + dx + 4]);
                    float tt = cosv - lab;
                    sum[j] = fmaf(tt, tt, sum[j]);
                    // - shift: cos(p, p-d) = dot_d(p-d)/(n(p)n(p-d))
                    float lab2 = (sp[j] == sr0[j - dx + 4] && sp[j] < 2) ? 1.f : 0.f;
                    float cos2 = dr[j - dx + 4] / (np[j] * nn0[j - dx + 4]);
                    float t2 = cos2 - lab2;
                    sum[j] = fmaf(t2, t2, sum[j]);
                }
            }
        }
        // ---- dy = 1,2 groups (maps 2..6 / 7..11; dx = -2..2) ----
#pragma unroll
        for (int d = 1; d <= 2; ++d) {
            int mb = (d == 1) ? 2 : 7;
            int srp[12], srm[12];
            float nnp[12], nnm[12];
            ldrow_i(seg + idx0 + d * W, x0, srp);
            ldrow_i(seg + idx0 - d * W, x0, srm);
            {
                float tp[12], tm[12];
                ldrow_f(normsq + idx0 + d * W, x0, tp);
                ldrow_f(normsq + idx0 - d * W, x0, tm);
#pragma unroll
                for (int k = 0; k < 12; ++k) {
                    nnp[k] = fmaxf(sqrtf(tp[k]), 1e-8f);
                    nnm[k] = fmaxf(sqrtf(tm[k]), 1e-8f);
                }
            }
#pragma unroll
            for (int dx = -2; dx <= 2; ++dx) {
                int i = mb + dx + 2;
                float4 dc = *((const float4*)(dots + (size_t)i * NPIX + idx0));
                float dcv[4] = {dc.x, dc.y, dc.z, dc.w};
                float drm[12];
                ldrow_f(dots + (size_t)i * NPIX + idx0 - d * W, x0, drm);
#pragma unroll
                for (int j = 0; j < 4; ++j) {
                    // + shift
                    float lab = (sp[j] == srp[j + dx + 4] && sp[j] < 2) ? 1.f : 0.f;
                    float cosv = dcv[j] / (np[j] * nnp[j + dx + 4]);
                    float tt = cosv - lab;
                    sum[j] = fmaf(tt, tt, sum[j]);
                    // - shift
                    float lab2 = (sp[j] == srm[j - dx + 4] && sp[j] < 2) ? 1.f : 0.f;
                    float cos2 = drm[j - dx + 4] / (np[j] * nnm[j - dx + 4]);
                    float t2 = cos2 - lab2;
                    sum[j] = fmaf(t2, t2, sum[j]);
                }
            }
        }

        float s = 0.0f;
#pragma unroll
        for (int j = 0; j < 4; ++j) s += vld[j] ? sum[j] : 0.0f;
        val = s * factor;
    }

    // block reduction: wave shuffle then LDS across 4 waves
    for (int o = 32; o > 0; o >>= 1)
        val += __shfl_down(val, o, 64);
    __shared__ float wsum[4];
    int lane = threadIdx.x & 63;
    int wid  = threadIdx.x >> 6;
    if (lane == 0) wsum[wid] = val;
    __syncthreads();
    if (threadIdx.x == 0) {
        float s = wsum[0] + wsum[1] + wsum[2] + wsum[3];
        atomicAdd(out, s);
    }
}

// ---------------------------------------------------------------------------
extern "C" void kernel_launch(void* const* d_in, const int* in_sizes, int n_in,
                              void* d_out, int out_size, void* d_ws, size_t ws_size,
                              hipStream_t stream) {
    const float* er  = (const float*)d_in[0];
    const int*   seg = (const int*)d_in[1];
    const int*   gtb = (const int*)d_in[2];
    float* out = (float*)d_out;

    float* ws   = (float*)d_ws;
    float* comb = ws;                            // 13 * NPIX floats (6.8 MB)
    int*   cnt  = (int*)(comb + NMAPS * NPIX);   // 8 ints
    int*   inc  = cnt + 8;                       // 8 ints

    hipLaunchKernelGGL(k_prep, dim3((NZ4 + 255) / 256), dim3(256), 0, stream,
                       (float4*)comb, cnt, inc, out);
    hipLaunchKernelGGL(k_corr, dim3(NCORRB + NSTATB), dim3(256), 0, stream,
                       er, seg, gtb, comb, cnt, inc);
    hipLaunchKernelGGL(k_loss, dim3(NPIX / 4 / 256), dim3(256), 0, stream,
                       comb, seg, gtb, cnt, inc, out);
}